// Round 4
// baseline (274.962 us; speedup 1.0000x reference)
//
#include <hip/hip_runtime.h>
#include <cstddef>

typedef unsigned short u16;
typedef unsigned int u32;
typedef __attribute__((ext_vector_type(8))) __bf16 bf16x8;
typedef __attribute__((ext_vector_type(4))) float f32x4;

constexpr int kB = 8, kC = 256, kCI = 128, kN = 4096, kM = 1024;
constexpr int kHM = 512;           // m per in-block half
constexpr int kCH = 64;            // m per chunk
constexpr int kNCH = kHM / kCH;    // 8 chunks per half
constexpr float kEPS = 1e-5f;
constexpr float kLOG2E = 1.44269504088896f;

__device__ __forceinline__ u16 f2bf(float f) {
    u32 u = __float_as_uint(f);
    u32 r = (u + 0x7fffu + ((u >> 16) & 1u)) >> 16;
    return (u16)r;
}

__device__ __forceinline__ void gload_lds16(const u16* g, u16* l) {
    __builtin_amdgcn_global_load_lds(
        (const __attribute__((address_space(1))) void*)g,
        (__attribute__((address_space(3))) void*)l, 16, 0, 0);
}

// ---------------------------------------------------------------------------
// MFMA producer conv1x1 body (optionally fused 2x2 avg-pool on input).
// Weights arrive as fp32 and are converted to bf16 (scaled by wscale) during
// the w_lds staging — prep kernel eliminated. bias scaled by bscale.
// ---------------------------------------------------------------------------
template <int POOL>
__device__ __forceinline__ void conv_body(const float* __restrict__ x,
                                          const float* __restrict__ Wf,
                                          const float* __restrict__ bias,
                                          float wscale, float bscale,
                                          u16* __restrict__ out, int Mn,
                                          int cmajor, int b, int n0,
                                          u16* w_lds, u16* x_lds) {
    int t = threadIdx.x;
    int w = t >> 6, lane = t & 63, l15 = lane & 15, quad = lane >> 4;
    int xn = t & 63, cbb = (t >> 6) * 2;

    f32x4 acc[8];
#pragma unroll
    for (int i = 0; i < 8; i++) acc[i] = (f32x4){0.f, 0.f, 0.f, 0.f};

    for (int c0 = 0; c0 < kC; c0 += 64) {
        __syncthreads();
#pragma unroll
        for (int i = 0; i < 4; i++) {
            int u = t + 256 * i;
            int ci = u >> 3, blk = u & 7;
            const float* ws = &Wf[ci * kC + c0 + blk * 8];
            float4 wa = *(const float4*)ws;
            float4 wb2 = *(const float4*)(ws + 4);
            bf16x8 pk;
            pk[0] = (__bf16)(wa.x * wscale);  pk[1] = (__bf16)(wa.y * wscale);
            pk[2] = (__bf16)(wa.z * wscale);  pk[3] = (__bf16)(wa.w * wscale);
            pk[4] = (__bf16)(wb2.x * wscale); pk[5] = (__bf16)(wb2.y * wscale);
            pk[6] = (__bf16)(wb2.z * wscale); pk[7] = (__bf16)(wb2.w * wscale);
            *(bf16x8*)&w_lds[ci * 72 + blk * 8] = pk;
        }
#pragma unroll
        for (int cc = 0; cc < 2; cc++) {
            int cb = cbb + cc;
            float f[8];
            if (POOL) {
                int p = n0 + xn, ph_ = p >> 5, pw_ = p & 31;
#pragma unroll
                for (int j = 0; j < 8; j++) {
                    const float* src = x + ((size_t)(b * kC + c0 + cb * 8 + j) * 64
                                            + 2 * ph_) * 64 + 2 * pw_;
                    float2 a = *(const float2*)src;
                    float2 b2 = *(const float2*)(src + 64);
                    f[j] = 0.25f * (a.x + a.y + b2.x + b2.y);
                }
            } else {
#pragma unroll
                for (int j = 0; j < 8; j++)
                    f[j] = x[(size_t)(b * kC + c0 + cb * 8 + j) * Mn + n0 + xn];
            }
            uint4 pk;
            pk.x = (u32)f2bf(f[0]) | ((u32)f2bf(f[1]) << 16);
            pk.y = (u32)f2bf(f[2]) | ((u32)f2bf(f[3]) << 16);
            pk.z = (u32)f2bf(f[4]) | ((u32)f2bf(f[5]) << 16);
            pk.w = (u32)f2bf(f[6]) | ((u32)f2bf(f[7]) << 16);
            *(uint4*)&x_lds[xn * 64 + ((cb ^ (xn & 7)) * 8)] = pk;
        }
        __syncthreads();

#pragma unroll
        for (int ks = 0; ks < 2; ks++) {
            int px = w * 16 + l15;
            bf16x8 xf = *(const bf16x8*)&x_lds[px * 64 + (((ks * 4 + quad) ^ (px & 7)) * 8)];
#pragma unroll
            for (int ct = 0; ct < 8; ct++) {
                bf16x8 wf = *(const bf16x8*)&w_lds[(ct * 16 + l15) * 72 + ks * 32 + quad * 8];
                if (cmajor)
                    acc[ct] = __builtin_amdgcn_mfma_f32_16x16x32_bf16(xf, wf, acc[ct], 0, 0, 0);
                else
                    acc[ct] = __builtin_amdgcn_mfma_f32_16x16x32_bf16(wf, xf, acc[ct], 0, 0, 0);
            }
        }
    }

    if (cmajor == 0) {
        int px = n0 + w * 16 + l15;
#pragma unroll
        for (int ct = 0; ct < 8; ct++) {
            int ci0 = ct * 16 + quad * 4;
            uint2 pk;
            pk.x = (u32)f2bf(acc[ct][0] + bias[ci0 + 0] * bscale) |
                   ((u32)f2bf(acc[ct][1] + bias[ci0 + 1] * bscale) << 16);
            pk.y = (u32)f2bf(acc[ct][2] + bias[ci0 + 2] * bscale) |
                   ((u32)f2bf(acc[ct][3] + bias[ci0 + 3] * bscale) << 16);
            *(uint2*)&out[(size_t)(b * Mn + px) * kCI + ci0] = pk;
        }
    } else {
        int px = n0 + w * 16 + quad * 4;
#pragma unroll
        for (int ct = 0; ct < 8; ct++) {
            int ci = ct * 16 + l15;
            float bs = bias[ci] * bscale;
            uint2 pk;
            pk.x = (u32)f2bf(acc[ct][0] + bs) | ((u32)f2bf(acc[ct][1] + bs) << 16);
            pk.y = (u32)f2bf(acc[ct][2] + bs) | ((u32)f2bf(acc[ct][3] + bs) << 16);
            *(uint2*)&out[(size_t)(b * kCI + ci) * Mn + px] = pk;
        }
    }
}

// ---------------------------------------------------------------------------
// FUSED producers: bx<64 -> theta conv (no pool, n-major, x log2e folded into
// weights+bias); bx in [64,80) -> phi conv (pool, n-major); bx in [80,96) ->
// g conv (pool, ci-major). 768 blocks (3/CU).
// ---------------------------------------------------------------------------
__global__ __launch_bounds__(256) void convs_kernel(const float* __restrict__ q,
                                                    const float* __restrict__ k,
                                                    const float* __restrict__ v,
                                                    const float* __restrict__ Wth,
                                                    const float* __restrict__ Wph,
                                                    const float* __restrict__ Wg,
                                                    const float* __restrict__ bth,
                                                    const float* __restrict__ bph,
                                                    const float* __restrict__ bg,
                                                    u16* __restrict__ theta,
                                                    u16* __restrict__ phi,
                                                    u16* __restrict__ g) {
    __shared__ __align__(16) u16 w_lds[128 * 72];
    __shared__ __align__(16) u16 x_lds[64 * 64];
    int bx = blockIdx.x, b = blockIdx.y;
    if (bx < 64) {
        conv_body<0>(k, Wth, bth, kLOG2E, kLOG2E, theta, kN, 0, b, bx * 64,
                     w_lds, x_lds);
    } else {
        int z = (bx >= 80);
        int n0 = (z ? (bx - 80) : (bx - 64)) * 64;
        conv_body<1>(z ? v : q, z ? Wg : Wph, z ? bg : bph, 1.0f, 1.0f,
                     z ? g : phi, kM, z, b, n0, w_lds, x_lds);
    }
}

// ---------------------------------------------------------------------------
// Flash attention, in-block m-split: 512 thr / 8 waves; waves 0-3 do
// m in [0,512), waves 4-7 do [512,1024). Combine via LDS at the end.
// 64-m chunks (8 iterations), double-buffered phi via global_load_lds
// (inverse-swizzled global src, linear LDS dest), ONE barrier per chunk.
// g read directly from global ([ci][m] -> contiguous 16B A-frags, L2-res).
// P scatter/read through per-wave LDS, reused across the two ks2 passes
// (per-wave DS ops are in-order -> WAR safe). exp2 domain + defer-max(8).
// LDS: phi 2x2x16KB + P 8KB + ml = 72.5KB -> 2 blocks/CU (grid-capped too).
// ---------------------------------------------------------------------------
__global__ __launch_bounds__(512, 4) void attn_kernel(const u16* __restrict__ theta,
                                                      const u16* __restrict__ phi,
                                                      const u16* __restrict__ g,
                                                      u16* __restrict__ y) {
    __shared__ __align__(16) u16 ph_lds[2][2][8192]; // [half][buf][ks:4][m:64][slot:4][8]
    __shared__ __align__(16) u16 p_lds[8 * 512];     // per-wave [col:16][k:32]
    __shared__ float mlsh[128];

    int t = threadIdx.x, b = blockIdx.y, n0 = blockIdx.x * 64;
    int w = t >> 6, lane = t & 63, l15 = lane & 15, quad = lane >> 4;
    int half = w >> 2, wl = w & 3, th = t & 255;
    int sw = (l15 >> 1) & 3;

    // theta B-frags in registers (16 n per wave; halves duplicate)
    bf16x8 thf[4];
    const u16* thB = theta + ((size_t)(b * kN) + n0 + wl * 16 + l15) * kCI;
#pragma unroll
    for (int ks = 0; ks < 4; ks++)
        thf[ks] = *(const bf16x8*)&thB[ks * 32 + quad * 8];

    f32x4 oacc[8];
#pragma unroll
    for (int ct = 0; ct < 8; ct++) oacc[ct] = (f32x4){0.f, 0.f, 0.f, 0.f};
    float m_ = -1e30f, l_ = 0.f;

    const u16* phB = phi + ((size_t)b * kM + half * kHM) * kCI;
    const u16* gB  = g + (size_t)b * kCI * kM + half * kHM;
    u16* pw = p_lds + w * 512;

    // inverse-swizzle staging map: linear LDS slot W = th + 256*i (i=0..3),
    // addr16 = W*8; decode ks=W>>8, m=(W>>2)&63, slot=W&3;
    // source cb = (ks<<2) | (slot ^ ((m>>1)&3)); go = m*128 + cb*8.
    int go_[4];
#pragma unroll
    for (int i = 0; i < 4; i++) {
        int W = th + 256 * i;
        int ks = W >> 8, m = (W >> 2) & 63, slot = W & 3;
        go_[i] = m * kCI + (((ks << 2) | (slot ^ ((m >> 1) & 3))) * 8);
    }

    // prologue: stage chunk 0 into buf 0 (dst base wave-uniform, lane*16B)
#pragma unroll
    for (int i = 0; i < 4; i++)
        gload_lds16(phB + go_[i], &ph_lds[half][0][(wl * 64 + 256 * i) * 8]);

    for (int ch = 0; ch < kNCH; ++ch) {
        asm volatile("s_waitcnt vmcnt(0)" ::: "memory");
        __syncthreads();   // chunk ch landed; prior reads of other buf done
        if (ch + 1 < kNCH) {
            const u16* src = phB + (ch + 1) * kCH * kCI;
            u16* dbuf = &ph_lds[half][(ch + 1) & 1][0];
#pragma unroll
            for (int i = 0; i < 4; i++)
                gload_lds16(src + go_[i], &dbuf[(wl * 64 + 256 * i) * 8]);
        }
        const u16* buf = &ph_lds[half][ch & 1][0];

        // S' = phi(64m x 128k) . theta^T : 4 mt-tiles, C-col = n (log2 dom)
        f32x4 sacc[4];
#pragma unroll
        for (int mt = 0; mt < 4; mt++) sacc[mt] = (f32x4){0.f, 0.f, 0.f, 0.f};
#pragma unroll
        for (int ks = 0; ks < 4; ks++)
#pragma unroll
            for (int mt = 0; mt < 4; mt++) {
                bf16x8 a = *(const bf16x8*)&buf[ks * 2048 + (mt * 16 + l15) * 32 +
                                                ((quad ^ sw) * 8)];
                sacc[mt] = __builtin_amdgcn_mfma_f32_16x16x32_bf16(a, thf[ks], sacc[mt], 0, 0, 0);
            }

        // online softmax (exp2 domain) with defer-max threshold 8
        float mc = -1e30f;
#pragma unroll
        for (int mt = 0; mt < 4; mt++)
#pragma unroll
            for (int r = 0; r < 4; r++) mc = fmaxf(mc, sacc[mt][r]);
        mc = fmaxf(mc, __shfl_xor(mc, 16, 64));
        mc = fmaxf(mc, __shfl_xor(mc, 32, 64));
        if (__any(mc > m_ + 8.0f)) {
            float mn = fmaxf(m_, mc);
            float al = exp2f(m_ - mn);
            m_ = mn;
            l_ *= al;
#pragma unroll
            for (int ct = 0; ct < 8; ct++)
#pragma unroll
                for (int r = 0; r < 4; r++) oacc[ct][r] *= al;
        }
        float rs = 0.f;
#pragma unroll
        for (int mt = 0; mt < 4; mt++)
#pragma unroll
            for (int r = 0; r < 4; r++) {
                float p = exp2f(sacc[mt][r] - m_);
                sacc[mt][r] = p;
                rs += p;
            }
        rs += __shfl_xor(rs, 16, 64);
        rs += __shfl_xor(rs, 32, 64);
        l_ += rs;

        // PV in two ks2 passes sharing one per-wave P buffer:
        // scatter 32 m of P' -> LDS, read B-frag, 8 MFMA with direct-g A-frags
        const u16* gC = gB + ch * kCH;
#pragma unroll
        for (int ks2 = 0; ks2 < 2; ks2++) {
#pragma unroll
            for (int mh = 0; mh < 2; mh++) {
                int mt = ks2 * 2 + mh;
#pragma unroll
                for (int h = 0; h < 2; h++) {
                    u32 d = (u32)f2bf(sacc[mt][2 * h]) |
                            ((u32)f2bf(sacc[mt][2 * h + 1]) << 16);
                    int m = mt * 16 + quad * 4 + 2 * h;
                    int kblk = (m >> 3) & 3;
                    int j = (quad & 1) * 4 + 2 * h;
                    *(u32*)&pw[l15 * 32 + ((kblk ^ sw) * 8) + j] = d;
                }
            }
            bf16x8 bfrag = *(const bf16x8*)&pw[l15 * 32 + ((quad ^ sw) * 8)];
#pragma unroll
            for (int ct = 0; ct < 8; ct++) {
                bf16x8 a = *(const bf16x8*)&gC[(size_t)(ct * 16 + l15) * kM +
                                               ks2 * 32 + quad * 8];
                oacc[ct] = __builtin_amdgcn_mfma_f32_16x16x32_bf16(a, bfrag, oacc[ct], 0, 0, 0);
            }
        }
    }

    // ---- in-block combine: half1 ships (O', m, l) through LDS ----
    __syncthreads();                         // all compute done; LDS reusable
    float* olds = (float*)&ph_lds[0][0][0];  // [64 n][128 ci] f32 (32KB)
    int nl = wl * 16 + l15;
    if (half == 1) {
#pragma unroll
        for (int ct = 0; ct < 8; ct++) {
            int s = (ct * 4 + quad) ^ (nl & 7);
            *(f32x4*)&olds[nl * 128 + s * 4] = oacc[ct];
        }
        if (quad == 0) { mlsh[2 * nl] = m_; mlsh[2 * nl + 1] = l_; }
    }
    __syncthreads();
    if (half == 0) {
        float m1 = mlsh[2 * nl], l1 = mlsh[2 * nl + 1];
        float mm = fmaxf(m_, m1);
        float w0 = exp2f(m_ - mm), w1 = exp2f(m1 - mm);
        float inv = 1.0f / (l_ * w0 + l1 * w1);
        float a0 = w0 * inv, a1 = w1 * inv;
        u16* yr = y + ((size_t)(b * kN) + n0 + nl) * kCI + quad * 4;
#pragma unroll
        for (int ct = 0; ct < 8; ct++) {
            int s = (ct * 4 + quad) ^ (nl & 7);
            f32x4 o1 = *(const f32x4*)&olds[nl * 128 + s * 4];
            uint2 pk;
            pk.x = (u32)f2bf(oacc[ct][0] * a0 + o1[0] * a1) |
                   ((u32)f2bf(oacc[ct][1] * a0 + o1[1] * a1) << 16);
            pk.y = (u32)f2bf(oacc[ct][2] * a0 + o1[2] * a1) |
                   ((u32)f2bf(oacc[ct][3] * a0 + o1[3] * a1) << 16);
            *(uint2*)&yr[ct * 16] = pk;
        }
    }
}

// ---------------------------------------------------------------------------
// MFMA final conv, split over co halves (blockIdx.z). BN folded into the
// epilogue: out = (Ww.y)*sc + bb + v, with Ww converted to bf16 at frag
// load time (prep kernel eliminated; weights are L2-resident).
// ---------------------------------------------------------------------------
__global__ __launch_bounds__(256) void final_kernel(const u16* __restrict__ y,
                                                    const float* __restrict__ Ww,
                                                    const float* __restrict__ gamma,
                                                    const float* __restrict__ beta,
                                                    const float* __restrict__ mean,
                                                    const float* __restrict__ var,
                                                    const float* __restrict__ bw,
                                                    const float* __restrict__ v,
                                                    float* __restrict__ out) {
    __shared__ __align__(16) u16 y_lds[64 * 136];
    int t = threadIdx.x, b = blockIdx.y, n0 = blockIdx.x * 64;
    int z = blockIdx.z;
    int w = t >> 6, lane = t & 63, l15 = lane & 15, quad = lane >> 4;

#pragma unroll
    for (int i = 0; i < 4; i++) {
        int u = t + 256 * i;
        int row = u >> 4, blk = u & 15;
        *(uint4*)&y_lds[row * 136 + blk * 8] =
            *(const uint4*)&y[(size_t)(b * kN + n0 + row) * kCI + blk * 8];
    }
    __syncthreads();

    bf16x8 af[4];
#pragma unroll
    for (int ks = 0; ks < 4; ks++)
        af[ks] = *(const bf16x8*)&y_lds[(w * 16 + l15) * 136 + ks * 32 + quad * 8];

#pragma unroll
    for (int ct = 0; ct < 8; ct++) {
        int co = z * 128 + ct * 16 + l15;
        f32x4 a = (f32x4){0.f, 0.f, 0.f, 0.f};
#pragma unroll
        for (int ks = 0; ks < 4; ks++) {
            const float* ws = &Ww[(size_t)co * kCI + ks * 32 + quad * 8];
            float4 wa = *(const float4*)ws;
            float4 wb2 = *(const float4*)(ws + 4);
            bf16x8 bf;
            bf[0] = (__bf16)wa.x;  bf[1] = (__bf16)wa.y;
            bf[2] = (__bf16)wa.z;  bf[3] = (__bf16)wa.w;
            bf[4] = (__bf16)wb2.x; bf[5] = (__bf16)wb2.y;
            bf[6] = (__bf16)wb2.z; bf[7] = (__bf16)wb2.w;
            a = __builtin_amdgcn_mfma_f32_16x16x32_bf16(af[ks], bf, a, 0, 0, 0);
        }
        float sc = gamma[co] * rsqrtf(var[co] + kEPS);
        float bbv = (bw[co] - mean[co]) * sc + beta[co];
        size_t base = (size_t)(b * kC + co) * kN + n0 + w * 16 + quad * 4;
        float4 vv = *(const float4*)&v[base];
        float4 ov;
        ov.x = a[0] * sc + bbv + vv.x;
        ov.y = a[1] * sc + bbv + vv.y;
        ov.z = a[2] * sc + bbv + vv.z;
        ov.w = a[3] * sc + bbv + vv.w;
        *(float4*)&out[base] = ov;
    }
}

// ---------------------------------------------------------------------------
extern "C" void kernel_launch(void* const* d_in, const int* in_sizes, int n_in,
                              void* d_out, int out_size, void* d_ws, size_t ws_size,
                              hipStream_t stream) {
    (void)in_sizes; (void)n_in; (void)out_size; (void)ws_size;
    const float* q     = (const float*)d_in[0];
    const float* k     = (const float*)d_in[1];
    const float* v     = (const float*)d_in[2];
    const float* Wg    = (const float*)d_in[3];
    const float* bg    = (const float*)d_in[4];
    const float* Wth   = (const float*)d_in[5];
    const float* bth   = (const float*)d_in[6];
    const float* Wph   = (const float*)d_in[7];
    const float* bph   = (const float*)d_in[8];
    const float* Ww    = (const float*)d_in[9];
    const float* bw    = (const float*)d_in[10];
    const float* gamma = (const float*)d_in[11];
    const float* beta  = (const float*)d_in[12];
    const float* mean  = (const float*)d_in[13];
    const float* var   = (const float*)d_in[14];
    float* out = (float*)d_out;

    u16* wsu = (u16*)d_ws;
    u16* theta = wsu;                       // 4M u16 (8MB)
    u16* phi   = theta + 4194304;           // 1M u16 (2MB)
    u16* gbuf  = phi + 1048576;             // 1M u16 (2MB)
    u16* ybuf  = gbuf + 1048576;            // 4M u16 (8MB)

    convs_kernel<<<dim3(96, 8), 256, 0, stream>>>(q, k, v, Wth, Wph, Wg,
                                                  bth, bph, bg, theta, phi, gbuf);
    attn_kernel<<<dim3(64, 8), 512, 0, stream>>>(theta, phi, gbuf, ybuf);
    final_kernel<<<dim3(64, 8, 2), 256, 0, stream>>>(ybuf, Ww, gamma, beta,
                                                     mean, var, bw, v, out);
}

// Round 5
// 266.058 us; speedup vs baseline: 1.0335x; 1.0335x over previous
//
#include <hip/hip_runtime.h>
#include <cstddef>

typedef unsigned short u16;
typedef unsigned int u32;
typedef __attribute__((ext_vector_type(8))) __bf16 bf16x8;
typedef __attribute__((ext_vector_type(4))) float f32x4;

constexpr int kB = 8, kC = 256, kCI = 128, kN = 4096, kM = 1024;
constexpr int kCH = 64;            // m per chunk
constexpr int kNCH = kM / kCH;     // 16 chunks
constexpr float kEPS = 1e-5f;
constexpr float kLOG2E = 1.44269504088896f;

__device__ __forceinline__ u16 f2bf(float f) {
    u32 u = __float_as_uint(f);
    u32 r = (u + 0x7fffu + ((u >> 16) & 1u)) >> 16;
    return (u16)r;
}

__device__ __forceinline__ void gload_lds16(const u16* g, u16* l) {
    __builtin_amdgcn_global_load_lds(
        (const __attribute__((address_space(1))) void*)g,
        (__attribute__((address_space(3))) void*)l, 16, 0, 0);
}

// ---------------------------------------------------------------------------
// prep: weights -> bf16; fold BN scale into Ww; bb = (bw-mean)*sc+beta
// Wth/bth scaled by log2(e) so softmax runs in exp2 domain.
// ---------------------------------------------------------------------------
__global__ __launch_bounds__(256) void prep_kernel(const float* __restrict__ Wth,
                                                   const float* __restrict__ bth,
                                                   const float* __restrict__ Wph,
                                                   const float* __restrict__ Wg,
                                                   const float* __restrict__ Ww,
                                                   const float* __restrict__ bw,
                                                   const float* __restrict__ gamma,
                                                   const float* __restrict__ beta,
                                                   const float* __restrict__ mean,
                                                   const float* __restrict__ var,
                                                   u16* __restrict__ Wthb,
                                                   u16* __restrict__ Wphb,
                                                   u16* __restrict__ Wgb,
                                                   u16* __restrict__ Wwsb,
                                                   float* __restrict__ bb,
                                                   float* __restrict__ bthl) {
    int idx = blockIdx.x * 256 + threadIdx.x;
    if (idx < 32768) {
        Wthb[idx] = f2bf(Wth[idx] * kLOG2E);
        if (idx < kCI) bthl[idx] = bth[idx] * kLOG2E;
    } else if (idx < 65536) {
        int j = idx - 32768; Wphb[j] = f2bf(Wph[j]);
    } else if (idx < 98304) {
        int j = idx - 65536; Wgb[j] = f2bf(Wg[j]);
    } else {
        int j = idx - 98304;
        int co = j >> 7;
        float sc = gamma[co] * rsqrtf(var[co] + kEPS);
        Wwsb[j] = f2bf(Ww[j] * sc);
        if ((j & 127) == 0) bb[co] = (bw[co] - mean[co]) * sc + beta[co];
    }
}

// ---------------------------------------------------------------------------
// MFMA producer conv1x1 body (optionally fused 2x2 avg-pool on input).
// ---------------------------------------------------------------------------
template <int POOL>
__device__ __forceinline__ void conv_body(const float* __restrict__ x,
                                          const u16* __restrict__ Wb,
                                          const float* __restrict__ bias,
                                          u16* __restrict__ out, int Mn,
                                          int cmajor, int b, int n0,
                                          u16* w_lds, u16* x_lds) {
    int t = threadIdx.x;
    int w = t >> 6, lane = t & 63, l15 = lane & 15, quad = lane >> 4;
    int xn = t & 63, cbb = (t >> 6) * 2;

    f32x4 acc[8];
#pragma unroll
    for (int i = 0; i < 8; i++) acc[i] = (f32x4){0.f, 0.f, 0.f, 0.f};

    for (int c0 = 0; c0 < kC; c0 += 64) {
        __syncthreads();
#pragma unroll
        for (int i = 0; i < 4; i++) {
            int u = t + 256 * i;
            int ci = u >> 3, blk = u & 7;
            *(uint4*)&w_lds[ci * 72 + blk * 8] =
                *(const uint4*)&Wb[ci * kC + c0 + blk * 8];
        }
#pragma unroll
        for (int cc = 0; cc < 2; cc++) {
            int cb = cbb + cc;
            float f[8];
            if (POOL) {
                int p = n0 + xn, ph_ = p >> 5, pw_ = p & 31;
#pragma unroll
                for (int j = 0; j < 8; j++) {
                    const float* src = x + ((size_t)(b * kC + c0 + cb * 8 + j) * 64
                                            + 2 * ph_) * 64 + 2 * pw_;
                    float2 a = *(const float2*)src;
                    float2 b2 = *(const float2*)(src + 64);
                    f[j] = 0.25f * (a.x + a.y + b2.x + b2.y);
                }
            } else {
#pragma unroll
                for (int j = 0; j < 8; j++)
                    f[j] = x[(size_t)(b * kC + c0 + cb * 8 + j) * Mn + n0 + xn];
            }
            uint4 pk;
            pk.x = (u32)f2bf(f[0]) | ((u32)f2bf(f[1]) << 16);
            pk.y = (u32)f2bf(f[2]) | ((u32)f2bf(f[3]) << 16);
            pk.z = (u32)f2bf(f[4]) | ((u32)f2bf(f[5]) << 16);
            pk.w = (u32)f2bf(f[6]) | ((u32)f2bf(f[7]) << 16);
            *(uint4*)&x_lds[xn * 64 + ((cb ^ (xn & 7)) * 8)] = pk;
        }
        __syncthreads();

#pragma unroll
        for (int ks = 0; ks < 2; ks++) {
            int px = w * 16 + l15;
            bf16x8 xf = *(const bf16x8*)&x_lds[px * 64 + (((ks * 4 + quad) ^ (px & 7)) * 8)];
#pragma unroll
            for (int ct = 0; ct < 8; ct++) {
                bf16x8 wf = *(const bf16x8*)&w_lds[(ct * 16 + l15) * 72 + ks * 32 + quad * 8];
                if (cmajor)
                    acc[ct] = __builtin_amdgcn_mfma_f32_16x16x32_bf16(xf, wf, acc[ct], 0, 0, 0);
                else
                    acc[ct] = __builtin_amdgcn_mfma_f32_16x16x32_bf16(wf, xf, acc[ct], 0, 0, 0);
            }
        }
    }

    if (cmajor == 0) {
        int px = n0 + w * 16 + l15;
#pragma unroll
        for (int ct = 0; ct < 8; ct++) {
            int ci0 = ct * 16 + quad * 4;
            uint2 pk;
            pk.x = (u32)f2bf(acc[ct][0] + bias[ci0 + 0]) |
                   ((u32)f2bf(acc[ct][1] + bias[ci0 + 1]) << 16);
            pk.y = (u32)f2bf(acc[ct][2] + bias[ci0 + 2]) |
                   ((u32)f2bf(acc[ct][3] + bias[ci0 + 3]) << 16);
            *(uint2*)&out[(size_t)(b * Mn + px) * kCI + ci0] = pk;
        }
    } else {
        int px = n0 + w * 16 + quad * 4;
#pragma unroll
        for (int ct = 0; ct < 8; ct++) {
            int ci = ct * 16 + l15;
            float bs = bias[ci];
            uint2 pk;
            pk.x = (u32)f2bf(acc[ct][0] + bs) | ((u32)f2bf(acc[ct][1] + bs) << 16);
            pk.y = (u32)f2bf(acc[ct][2] + bs) | ((u32)f2bf(acc[ct][3] + bs) << 16);
            *(uint2*)&out[(size_t)(b * kCI + ci) * Mn + px] = pk;
        }
    }
}

// ---------------------------------------------------------------------------
// FUSED producers: bx<64 -> theta conv (no pool, n-major, log2e-folded);
// bx in [64,80) -> phi conv (pool, n-major); bx in [80,96) -> g conv
// (pool, ci-major). 768 blocks (3/CU).
// ---------------------------------------------------------------------------
__global__ __launch_bounds__(256) void convs_kernel(const float* __restrict__ q,
                                                    const float* __restrict__ k,
                                                    const float* __restrict__ v,
                                                    const u16* __restrict__ Wthb,
                                                    const u16* __restrict__ Wphb,
                                                    const u16* __restrict__ Wgb,
                                                    const float* __restrict__ bthl,
                                                    const float* __restrict__ bph,
                                                    const float* __restrict__ bg,
                                                    u16* __restrict__ theta,
                                                    u16* __restrict__ phi,
                                                    u16* __restrict__ g) {
    __shared__ __align__(16) u16 w_lds[128 * 72];
    __shared__ __align__(16) u16 x_lds[64 * 64];
    int bx = blockIdx.x, b = blockIdx.y;
    if (bx < 64) {
        conv_body<0>(k, Wthb, bthl, theta, kN, 0, b, bx * 64, w_lds, x_lds);
    } else {
        int z = (bx >= 80);
        int n0 = (z ? (bx - 80) : (bx - 64)) * 64;
        conv_body<1>(z ? v : q, z ? Wgb : Wphb, z ? bg : bph, z ? g : phi,
                     kM, z, b, n0, w_lds, x_lds);
    }
}

// ---------------------------------------------------------------------------
// Software-pipelined flash attention: 256 thr / 4 waves, full m per block.
// Per step (one barrier): vmcnt(0)+barrier -> STAGE(c+2, DMA) ->
// QK(c+1) [MFMA from LDS] || softmax(c)+PV(c) [VALU + MFMA + direct-g] —
// the barrier-free region lets the scheduler overlap QK's MFMA/ds_read with
// softmax's VALU chain (the round-0..4 serial bottleneck).
// phi: double-buffered global_load_lds w/ inverse-swizzled source.
// g: direct 16B global A-frags ([ci][m] layout, L2-resident).
// exp2 domain + defer-max(8); cross-quad l-reduce deferred to epilogue.
// LDS 36KB; launch_bounds(256,2) -> no spill possible (256 reg budget).
// ---------------------------------------------------------------------------
__global__ __launch_bounds__(256, 2) void attn_kernel(const u16* __restrict__ theta,
                                                      const u16* __restrict__ phi,
                                                      const u16* __restrict__ g,
                                                      u16* __restrict__ y) {
    __shared__ __align__(16) u16 ph_lds[2][8192]; // [buf][ks:4][m:64][slot:4][8]
    __shared__ __align__(16) u16 p_lds[4 * 512];  // per-wave [col:16][k:32]

    int t = threadIdx.x, b = blockIdx.y, n0 = blockIdx.x * 64;
    int w = t >> 6, lane = t & 63, l15 = lane & 15, quad = lane >> 4;
    int sw = (l15 >> 1) & 3;

    bf16x8 thf[4];
    const u16* thB = theta + ((size_t)(b * kN) + n0 + w * 16 + l15) * kCI;
#pragma unroll
    for (int ks = 0; ks < 4; ks++)
        thf[ks] = *(const bf16x8*)&thB[ks * 32 + quad * 8];

    f32x4 oacc[8];
#pragma unroll
    for (int ct = 0; ct < 8; ct++) oacc[ct] = (f32x4){0.f, 0.f, 0.f, 0.f};
    float m_ = -1e30f, l_ = 0.f;

    const u16* phB = phi + (size_t)b * kM * kCI;
    const u16* gB  = g + (size_t)b * kCI * kM;
    u16* pw = p_lds + w * 512;

    // inverse-swizzle staging map: linear LDS slot W = t + 256*i (i=0..3);
    // decode ks=W>>8, m=(W>>2)&63, slot=W&3; src cb=(ks<<2)|(slot^((m>>1)&3)).
    int go_[4];
#pragma unroll
    for (int i = 0; i < 4; i++) {
        int W = t + 256 * i;
        int ks = W >> 8, m = (W >> 2) & 63, slot = W & 3;
        go_[i] = m * kCI + (((ks << 2) | (slot ^ ((m >> 1) & 3))) * 8);
    }

    auto STAGE = [&](int buf, int ch) {
        const u16* src = phB + ch * kCH * kCI;
#pragma unroll
        for (int i = 0; i < 4; i++)
            gload_lds16(src + go_[i], &ph_lds[buf][(w * 64 + 256 * i) * 8]);
    };

    auto QK = [&](f32x4 (&sacc)[4], int buf) {
#pragma unroll
        for (int mt = 0; mt < 4; mt++) sacc[mt] = (f32x4){0.f, 0.f, 0.f, 0.f};
        const u16* bufp = &ph_lds[buf][0];
#pragma unroll
        for (int ks = 0; ks < 4; ks++)
#pragma unroll
            for (int mt = 0; mt < 4; mt++) {
                bf16x8 a = *(const bf16x8*)&bufp[ks * 2048 + (mt * 16 + l15) * 32 +
                                                 ((quad ^ sw) * 8)];
                sacc[mt] = __builtin_amdgcn_mfma_f32_16x16x32_bf16(a, thf[ks], sacc[mt], 0, 0, 0);
            }
    };

    auto SMPV = [&](f32x4 (&sacc)[4], int ch) {
        // online softmax (exp2 domain), defer-max(8), per-lane partial l
        float mc = -1e30f;
#pragma unroll
        for (int mt = 0; mt < 4; mt++)
#pragma unroll
            for (int r = 0; r < 4; r++) mc = fmaxf(mc, sacc[mt][r]);
        mc = fmaxf(mc, __shfl_xor(mc, 16, 64));
        mc = fmaxf(mc, __shfl_xor(mc, 32, 64));
        if (__any(mc > m_ + 8.0f)) {
            float mn = fmaxf(m_, mc);
            float al = exp2f(m_ - mn);
            m_ = mn;
            l_ *= al;
#pragma unroll
            for (int ct = 0; ct < 8; ct++)
#pragma unroll
                for (int r = 0; r < 4; r++) oacc[ct][r] *= al;
        }
        float rs = 0.f;
#pragma unroll
        for (int mt = 0; mt < 4; mt++)
#pragma unroll
            for (int r = 0; r < 4; r++) {
                float p = exp2f(sacc[mt][r] - m_);
                sacc[mt][r] = p;
                rs += p;
            }
        l_ += rs;   // per-lane partial; cross-quad reduce at epilogue

        // PV in two ks2 passes sharing the per-wave P buffer
        const u16* gC = gB + ch * kCH;
#pragma unroll
        for (int ks2 = 0; ks2 < 2; ks2++) {
#pragma unroll
            for (int mh = 0; mh < 2; mh++) {
                int mt = ks2 * 2 + mh;
#pragma unroll
                for (int h = 0; h < 2; h++) {
                    u32 d = (u32)f2bf(sacc[mt][2 * h]) |
                            ((u32)f2bf(sacc[mt][2 * h + 1]) << 16);
                    int m = mt * 16 + quad * 4 + 2 * h;
                    int kblk = (m >> 3) & 3;
                    int j = (quad & 1) * 4 + 2 * h;
                    *(u32*)&pw[l15 * 32 + ((kblk ^ sw) * 8) + j] = d;
                }
            }
            bf16x8 bfrag = *(const bf16x8*)&pw[l15 * 32 + ((quad ^ sw) * 8)];
#pragma unroll
            for (int ct = 0; ct < 8; ct++) {
                bf16x8 a = *(const bf16x8*)&gC[(size_t)(ct * 16 + l15) * kM +
                                               ks2 * 32 + quad * 8];
                oacc[ct] = __builtin_amdgcn_mfma_f32_16x16x32_bf16(a, bfrag, oacc[ct], 0, 0, 0);
            }
        }
    };

    f32x4 sA[4], sB[4];

    // prologue
    STAGE(0, 0);
    asm volatile("s_waitcnt vmcnt(0)" ::: "memory");
    __syncthreads();
    STAGE(1, 1);
    QK(sA, 0);

    // pipelined main loop: explicit even/odd unroll (static reg names)
    for (int c = 0; c < kNCH; c += 2) {
        // step c: SMPV(sA, c), QK(sB, c+1) overlapped
        asm volatile("s_waitcnt vmcnt(0)" ::: "memory");
        __syncthreads();
        if (c + 2 < kNCH) STAGE(0, c + 2);
        QK(sB, 1);
        SMPV(sA, c);
        // step c+1
        asm volatile("s_waitcnt vmcnt(0)" ::: "memory");
        __syncthreads();
        if (c + 3 < kNCH) STAGE(1, c + 3);
        if (c + 2 < kNCH) QK(sA, 0);
        SMPV(sB, c + 1);
    }

    // epilogue: finish l reduce, normalize, write y[n][ci]
    l_ += __shfl_xor(l_, 16, 64);
    l_ += __shfl_xor(l_, 32, 64);
    float inv = 1.0f / l_;
    int n = n0 + w * 16 + l15;
    u16* yr = y + ((size_t)(b * kN) + n) * kCI + quad * 4;
#pragma unroll
    for (int ct = 0; ct < 8; ct++) {
        uint2 pk;
        pk.x = (u32)f2bf(oacc[ct][0] * inv) | ((u32)f2bf(oacc[ct][1] * inv) << 16);
        pk.y = (u32)f2bf(oacc[ct][2] * inv) | ((u32)f2bf(oacc[ct][3] * inv) << 16);
        *(uint2*)&yr[ct * 16] = pk;
    }
}

// ---------------------------------------------------------------------------
// MFMA final conv, split over co halves (blockIdx.z):
// out[b][co][n] = Wws(bf16, BN-folded) . y + bb[co] + v[b][co][n]
// ---------------------------------------------------------------------------
__global__ __launch_bounds__(256) void final_kernel(const u16* __restrict__ y,
                                                    const u16* __restrict__ Wws,
                                                    const float* __restrict__ bb,
                                                    const float* __restrict__ v,
                                                    float* __restrict__ out) {
    __shared__ __align__(16) u16 y_lds[64 * 136];
    int t = threadIdx.x, b = blockIdx.y, n0 = blockIdx.x * 64;
    int z = blockIdx.z;
    int w = t >> 6, lane = t & 63, l15 = lane & 15, quad = lane >> 4;

#pragma unroll
    for (int i = 0; i < 4; i++) {
        int u = t + 256 * i;
        int row = u >> 4, blk = u & 15;
        *(uint4*)&y_lds[row * 136 + blk * 8] =
            *(const uint4*)&y[(size_t)(b * kN + n0 + row) * kCI + blk * 8];
    }
    __syncthreads();

    bf16x8 af[4];
#pragma unroll
    for (int ks = 0; ks < 4; ks++)
        af[ks] = *(const bf16x8*)&y_lds[(w * 16 + l15) * 136 + ks * 32 + quad * 8];

#pragma unroll
    for (int ct = 0; ct < 8; ct++) {
        int co = z * 128 + ct * 16 + l15;
        f32x4 a = (f32x4){0.f, 0.f, 0.f, 0.f};
#pragma unroll
        for (int ks = 0; ks < 4; ks++) {
            bf16x8 bf = *(const bf16x8*)&Wws[(size_t)co * kCI + ks * 32 + quad * 8];
            a = __builtin_amdgcn_mfma_f32_16x16x32_bf16(af[ks], bf, a, 0, 0, 0);
        }
        float bbv = bb[co];
        size_t base = (size_t)(b * kC + co) * kN + n0 + w * 16 + quad * 4;
        float4 vv = *(const float4*)&v[base];
        float4 ov;
        ov.x = a[0] + bbv + vv.x;
        ov.y = a[1] + bbv + vv.y;
        ov.z = a[2] + bbv + vv.z;
        ov.w = a[3] + bbv + vv.w;
        *(float4*)&out[base] = ov;
    }
}

// ---------------------------------------------------------------------------
extern "C" void kernel_launch(void* const* d_in, const int* in_sizes, int n_in,
                              void* d_out, int out_size, void* d_ws, size_t ws_size,
                              hipStream_t stream) {
    (void)in_sizes; (void)n_in; (void)out_size; (void)ws_size;
    const float* q     = (const float*)d_in[0];
    const float* k     = (const float*)d_in[1];
    const float* v     = (const float*)d_in[2];
    const float* Wg    = (const float*)d_in[3];
    const float* bg    = (const float*)d_in[4];
    const float* Wth   = (const float*)d_in[5];
    const float* bth   = (const float*)d_in[6];
    const float* Wph   = (const float*)d_in[7];
    const float* bph   = (const float*)d_in[8];
    const float* Ww    = (const float*)d_in[9];
    const float* bw    = (const float*)d_in[10];
    const float* gamma = (const float*)d_in[11];
    const float* beta  = (const float*)d_in[12];
    const float* mean  = (const float*)d_in[13];
    const float* var   = (const float*)d_in[14];
    float* out = (float*)d_out;

    u16* wsu = (u16*)d_ws;
    u16*   theta = wsu;                       // 4M u16 (8MB)
    u16*   phi   = theta + 4194304;           // 1M u16 (2MB)
    u16*   gbuf  = phi + 1048576;             // 1M u16 (2MB)
    u16*   ybuf  = gbuf + 1048576;            // 4M u16 (8MB)
    u16*   Wthb  = ybuf + 4194304;
    u16*   Wphb  = Wthb + 32768;
    u16*   Wgb   = Wphb + 32768;
    u16*   Wwsb  = Wgb + 32768;
    float* bbuf  = (float*)(Wwsb + 32768);    // 256 f32
    float* bthl  = bbuf + 256;                // 128 f32

    prep_kernel<<<dim3(512), 256, 0, stream>>>(Wth, bth, Wph, Wg, Ww, bw, gamma, beta,
                                               mean, var, Wthb, Wphb, Wgb, Wwsb,
                                               bbuf, bthl);
    convs_kernel<<<dim3(96, 8), 256, 0, stream>>>(q, k, v, Wthb, Wphb, Wgb,
                                                  bthl, bph, bg, theta, phi, gbuf);
    attn_kernel<<<dim3(64, 8), 256, 0, stream>>>(theta, phi, gbuf, ybuf);
    final_kernel<<<dim3(64, 8, 2), 256, 0, stream>>>(ybuf, Wwsb, bbuf, v, out);
}

// Round 6
// 254.892 us; speedup vs baseline: 1.0787x; 1.0438x over previous
//
#include <hip/hip_runtime.h>
#include <cstddef>

typedef unsigned short u16;
typedef unsigned int u32;
typedef __attribute__((ext_vector_type(8))) __bf16 bf16x8;
typedef __attribute__((ext_vector_type(4))) float f32x4;

constexpr int kB = 8, kC = 256, kCI = 128, kN = 4096, kM = 1024;
constexpr float kEPS = 1e-5f;
constexpr float kLOG2E = 1.44269504088896f;

__device__ __forceinline__ u16 f2bf(float f) {
    u32 u = __float_as_uint(f);
    u32 r = (u + 0x7fffu + ((u >> 16) & 1u)) >> 16;
    return (u16)r;
}

// ---------------------------------------------------------------------------
// prep: weights -> bf16; fold BN scale into Ww; bb = (bw-mean)*sc+beta
// Wth/bth scaled by log2(e) so softmax runs in exp2 domain.
// ---------------------------------------------------------------------------
__global__ __launch_bounds__(256) void prep_kernel(const float* __restrict__ Wth,
                                                   const float* __restrict__ bth,
                                                   const float* __restrict__ Wph,
                                                   const float* __restrict__ Wg,
                                                   const float* __restrict__ Ww,
                                                   const float* __restrict__ bw,
                                                   const float* __restrict__ gamma,
                                                   const float* __restrict__ beta,
                                                   const float* __restrict__ mean,
                                                   const float* __restrict__ var,
                                                   u16* __restrict__ Wthb,
                                                   u16* __restrict__ Wphb,
                                                   u16* __restrict__ Wgb,
                                                   u16* __restrict__ Wwsb,
                                                   float* __restrict__ bb,
                                                   float* __restrict__ bthl) {
    int idx = blockIdx.x * 256 + threadIdx.x;
    if (idx < 32768) {
        Wthb[idx] = f2bf(Wth[idx] * kLOG2E);
        if (idx < kCI) bthl[idx] = bth[idx] * kLOG2E;
    } else if (idx < 65536) {
        int j = idx - 32768; Wphb[j] = f2bf(Wph[j]);
    } else if (idx < 98304) {
        int j = idx - 65536; Wgb[j] = f2bf(Wg[j]);
    } else {
        int j = idx - 98304;
        int co = j >> 7;
        float sc = gamma[co] * rsqrtf(var[co] + kEPS);
        Wwsb[j] = f2bf(Ww[j] * sc);
        if ((j & 127) == 0) bb[co] = (bw[co] - mean[co]) * sc + beta[co];
    }
}

// ---------------------------------------------------------------------------
// Whole-K conv1x1 body: stage x tile (64 px x 256 c, bf16, slot-swizzled)
// ONCE into 32KB LDS, ONE barrier, then 8 K-steps of MFMA with weight
// fragments loaded DIRECTLY from global (bf16, L2-resident, 16B/frag —
// same pattern as final_kernel). 4 blocks/CU co-resident.
// ---------------------------------------------------------------------------
template <int POOL>
__device__ __forceinline__ void conv_body(const float* __restrict__ x,
                                          const u16* __restrict__ Wb,
                                          const float* __restrict__ bias,
                                          u16* __restrict__ out, int Mn,
                                          int cmajor, int b, int n0,
                                          u16* x_lds) {
    int t = threadIdx.x;
    int w = t >> 6, lane = t & 63, l15 = lane & 15, quad = lane >> 4;
    int px = t & 63, cb8 = t >> 6;   // this thread stages c-block-of-64 cb8 for pixel px

    // ---- stage x whole-K: c = cb*8+j, cb = cb8*8+cc8 ----
    for (int cc8 = 0; cc8 < 8; cc8++) {
        int cb = cb8 * 8 + cc8;
        int c0 = cb * 8;
        float f[8];
        if (POOL) {
            int p = n0 + px, ph_ = p >> 5, pw_ = p & 31;
#pragma unroll
            for (int j = 0; j < 8; j++) {
                const float* src = x + ((size_t)(b * kC + c0 + j) * 64
                                        + 2 * ph_) * 64 + 2 * pw_;
                float2 a = *(const float2*)src;
                float2 b2 = *(const float2*)(src + 64);
                f[j] = 0.25f * (a.x + a.y + b2.x + b2.y);
            }
        } else {
#pragma unroll
            for (int j = 0; j < 8; j++)
                f[j] = x[(size_t)(b * kC + c0 + j) * Mn + n0 + px];
        }
        uint4 pk;
        pk.x = (u32)f2bf(f[0]) | ((u32)f2bf(f[1]) << 16);
        pk.y = (u32)f2bf(f[2]) | ((u32)f2bf(f[3]) << 16);
        pk.z = (u32)f2bf(f[4]) | ((u32)f2bf(f[5]) << 16);
        pk.w = (u32)f2bf(f[6]) | ((u32)f2bf(f[7]) << 16);
        *(uint4*)&x_lds[px * 256 + ((cb ^ (px & 7)) * 8)] = pk;
    }
    __syncthreads();

    // ---- 8 K-steps: xf from LDS, wf direct from global (L2) ----
    f32x4 acc[8];
#pragma unroll
    for (int i = 0; i < 8; i++) acc[i] = (f32x4){0.f, 0.f, 0.f, 0.f};

    int rpx = w * 16 + l15;
#pragma unroll
    for (int ks = 0; ks < 8; ks++) {
        bf16x8 xf = *(const bf16x8*)&x_lds[rpx * 256 +
                                           (((ks * 4 + quad) ^ (rpx & 7)) * 8)];
#pragma unroll
        for (int ct = 0; ct < 8; ct++) {
            bf16x8 wf = *(const bf16x8*)&Wb[(ct * 16 + l15) * kC + ks * 32 + quad * 8];
            if (cmajor)
                acc[ct] = __builtin_amdgcn_mfma_f32_16x16x32_bf16(xf, wf, acc[ct], 0, 0, 0);
            else
                acc[ct] = __builtin_amdgcn_mfma_f32_16x16x32_bf16(wf, xf, acc[ct], 0, 0, 0);
        }
    }

    if (cmajor == 0) {
        int opx = n0 + w * 16 + l15;
#pragma unroll
        for (int ct = 0; ct < 8; ct++) {
            int ci0 = ct * 16 + quad * 4;
            uint2 pk;
            pk.x = (u32)f2bf(acc[ct][0] + bias[ci0 + 0]) |
                   ((u32)f2bf(acc[ct][1] + bias[ci0 + 1]) << 16);
            pk.y = (u32)f2bf(acc[ct][2] + bias[ci0 + 2]) |
                   ((u32)f2bf(acc[ct][3] + bias[ci0 + 3]) << 16);
            *(uint2*)&out[(size_t)(b * Mn + opx) * kCI + ci0] = pk;
        }
    } else {
        int opx = n0 + w * 16 + quad * 4;
#pragma unroll
        for (int ct = 0; ct < 8; ct++) {
            int ci = ct * 16 + l15;
            float bs = bias[ci];
            uint2 pk;
            pk.x = (u32)f2bf(acc[ct][0] + bs) | ((u32)f2bf(acc[ct][1] + bs) << 16);
            pk.y = (u32)f2bf(acc[ct][2] + bs) | ((u32)f2bf(acc[ct][3] + bs) << 16);
            *(uint2*)&out[(size_t)(b * kCI + ci) * Mn + opx] = pk;
        }
    }
}

// ---------------------------------------------------------------------------
// FUSED producers: bx<64 -> theta conv (no pool, n-major, log2e-folded);
// bx in [64,80) -> phi conv (pool, n-major); bx in [80,96) -> g conv
// (pool, ci-major). 768 blocks; 32KB LDS -> 4 blocks/CU.
// ---------------------------------------------------------------------------
__global__ __launch_bounds__(256, 4) void convs_kernel(const float* __restrict__ q,
                                                       const float* __restrict__ k,
                                                       const float* __restrict__ v,
                                                       const u16* __restrict__ Wthb,
                                                       const u16* __restrict__ Wphb,
                                                       const u16* __restrict__ Wgb,
                                                       const float* __restrict__ bthl,
                                                       const float* __restrict__ bph,
                                                       const float* __restrict__ bg,
                                                       u16* __restrict__ theta,
                                                       u16* __restrict__ phi,
                                                       u16* __restrict__ g) {
    __shared__ __align__(16) u16 x_lds[64 * 256];   // 32KB
    int bx = blockIdx.x, b = blockIdx.y;
    if (bx < 64) {
        conv_body<0>(k, Wthb, bthl, theta, kN, 0, b, bx * 64, x_lds);
    } else {
        int z = (bx >= 80);
        int n0 = (z ? (bx - 80) : (bx - 64)) * 64;
        conv_body<1>(z ? v : q, z ? Wgb : Wphb, z ? bg : bph, z ? g : phi,
                     kM, z, b, n0, x_lds);
    }
}

// ---------------------------------------------------------------------------
// Transposed flash attention (round-0 proven structure), bf16 MFMA,
// swizzled conflict-free LDS. theta [B][N][CI], phi [B][M][CI],
// g [B][CI][M] (bf16); y bf16 [B][N][CI].
// S' = phi . theta^T (C-col = n), O' = G^T . P' (C-col = n).
// 256 thr / 4 waves; wave owns 16 n; m-chunks of 64; phi AND g staged to
// LDS via reg loads (direct-g variants all measured slower, r3-r5).
// Deltas vs r0: exp2 domain (theta pre-scaled), defer-max(8), deferred
// cross-quad l-reduce (epilogue).
// ---------------------------------------------------------------------------
__global__ __launch_bounds__(256) void attn_kernel(const u16* __restrict__ theta,
                                                   const u16* __restrict__ phi,
                                                   const u16* __restrict__ g,
                                                   u16* __restrict__ y) {
    __shared__ __align__(16) u16 ph_lds[8192];   // [ks:4][m:64][kblk:4][8]  16KB
    __shared__ __align__(16) u16 g_lds[8192];    // [ks2:2][ci:128][kblk:4][8] 16KB
    __shared__ __align__(16) u16 p_lds[4096];    // [wave:4][frag:2][col:16][k:32] 8KB

    int t = threadIdx.x, b = blockIdx.y, n0 = blockIdx.x * 64;
    int w = t >> 6, lane = t & 63, l15 = lane & 15, quad = lane >> 4;
    int sw = (l15 >> 1) & 3;

    // theta B-frags in registers for the whole kernel (16 n per wave)
    bf16x8 thf[4];
    const u16* thB = theta + ((size_t)(b * kN) + n0 + w * 16 + l15) * kCI;
#pragma unroll
    for (int ks = 0; ks < 4; ks++)
        thf[ks] = *(const bf16x8*)&thB[ks * 32 + quad * 8];

    f32x4 oacc[8];
#pragma unroll
    for (int ct = 0; ct < 8; ct++) oacc[ct] = (f32x4){0.f, 0.f, 0.f, 0.f};
    float m_ = -1e30f, l_ = 0.f;

    const u16* phB = phi + (size_t)b * kM * kCI;
    const u16* gB  = g   + (size_t)b * kCI * kM;
    u16* pw = p_lds + w * 1024;

    for (int c0 = 0; c0 < kM; c0 += 64) {
        __syncthreads();
        // stage phi chunk [64 m][128 ci] -> [ks][m][kblk^((m>>1)&3)]
#pragma unroll
        for (int it = 0; it < 4; it++) {
            int u = t + 256 * it;
            int row = u >> 4, cb = u & 15;
            *(uint4*)&ph_lds[(cb >> 2) * 2048 + row * 32 + (((cb & 3) ^ ((row >> 1) & 3)) * 8)] =
                *(const uint4*)&phB[(size_t)(c0 + row) * kCI + cb * 8];
        }
        // stage g chunk [128 ci][64 m] -> [ks2][ci][kblk^((ci>>1)&3)]
#pragma unroll
        for (int it = 0; it < 4; it++) {
            int u = t + 256 * it;
            int ci = u >> 3, mb = u & 7;
            *(uint4*)&g_lds[(mb >> 2) * 4096 + ci * 32 + (((mb & 3) ^ ((ci >> 1) & 3)) * 8)] =
                *(const uint4*)&gB[(size_t)ci * kM + c0 + mb * 8];
        }
        __syncthreads();

        // S' = phi(64m x 128k) . theta^T : 4 mt-tiles, C-col = n (log2 dom)
        f32x4 sacc[4];
#pragma unroll
        for (int mt = 0; mt < 4; mt++) sacc[mt] = (f32x4){0.f, 0.f, 0.f, 0.f};
#pragma unroll
        for (int ks = 0; ks < 4; ks++)
#pragma unroll
            for (int mt = 0; mt < 4; mt++) {
                bf16x8 a = *(const bf16x8*)&ph_lds[ks * 2048 + (mt * 16 + l15) * 32 +
                                                   ((quad ^ sw) * 8)];
                sacc[mt] = __builtin_amdgcn_mfma_f32_16x16x32_bf16(a, thf[ks], sacc[mt], 0, 0, 0);
            }

        // online softmax over m (exp2 domain, defer-max(8), per-lane l)
        float mc = -1e30f;
#pragma unroll
        for (int mt = 0; mt < 4; mt++)
#pragma unroll
            for (int r = 0; r < 4; r++) mc = fmaxf(mc, sacc[mt][r]);
        mc = fmaxf(mc, __shfl_xor(mc, 16, 64));
        mc = fmaxf(mc, __shfl_xor(mc, 32, 64));
        if (__any(mc > m_ + 8.0f)) {
            float mn = fmaxf(m_, mc);
            float al = exp2f(m_ - mn);
            m_ = mn;
            l_ *= al;
#pragma unroll
            for (int ct = 0; ct < 8; ct++)
#pragma unroll
                for (int r = 0; r < 4; r++) oacc[ct][r] *= al;
        }
        float rs = 0.f;
#pragma unroll
        for (int mt = 0; mt < 4; mt++)
#pragma unroll
            for (int r = 0; r < 4; r++) {
                float p = exp2f(sacc[mt][r] - m_);
                sacc[mt][r] = p;
                rs += p;
            }
        l_ += rs;   // cross-quad reduce deferred to epilogue

        // scatter P' -> per-wave frag LDS [frag][col=l15][k] swizzled
#pragma unroll
        for (int mt = 0; mt < 4; mt++)
#pragma unroll
            for (int h = 0; h < 2; h++) {
                u32 d = (u32)f2bf(sacc[mt][2 * h]) | ((u32)f2bf(sacc[mt][2 * h + 1]) << 16);
                int m = mt * 16 + quad * 4 + 2 * h;
                int frag = m >> 5;
                int kblk = ((m >> 3) & 3);
                int j = (quad & 1) * 4 + 2 * h;
                *(u32*)&pw[frag * 512 + l15 * 32 + ((kblk ^ sw) * 8) + j] = d;
            }

        // O' += G^T(128ci x 64m) . P'   (per-wave p buffer, no barrier)
#pragma unroll
        for (int ks2 = 0; ks2 < 2; ks2++) {
            bf16x8 bfrag = *(const bf16x8*)&pw[ks2 * 512 + l15 * 32 + ((quad ^ sw) * 8)];
#pragma unroll
            for (int ct = 0; ct < 8; ct++) {
                bf16x8 a = *(const bf16x8*)&g_lds[ks2 * 4096 + (ct * 16 + l15) * 32 +
                                                  ((quad ^ sw) * 8)];
                oacc[ct] = __builtin_amdgcn_mfma_f32_16x16x32_bf16(a, bfrag, oacc[ct], 0, 0, 0);
            }
        }
    }

    // epilogue: finish l reduce, y[n][ci] = O'/l ; n = col = l15
    l_ += __shfl_xor(l_, 16, 64);
    l_ += __shfl_xor(l_, 32, 64);
    float inv = 1.0f / l_;
    int n = n0 + w * 16 + l15;
    u16* yr = y + ((size_t)(b * kN) + n) * kCI + quad * 4;
#pragma unroll
    for (int ct = 0; ct < 8; ct++) {
        uint2 pk;
        pk.x = (u32)f2bf(oacc[ct][0] * inv) | ((u32)f2bf(oacc[ct][1] * inv) << 16);
        pk.y = (u32)f2bf(oacc[ct][2] * inv) | ((u32)f2bf(oacc[ct][3] * inv) << 16);
        *(uint2*)&yr[ct * 16] = pk;
    }
}

// ---------------------------------------------------------------------------
// MFMA final conv, split over co halves (blockIdx.z):
// out[b][co][n] = Wws(bf16, BN-folded) . y + bb[co] + v[b][co][n]
// ---------------------------------------------------------------------------
__global__ __launch_bounds__(256) void final_kernel(const u16* __restrict__ y,
                                                    const u16* __restrict__ Wws,
                                                    const float* __restrict__ bb,
                                                    const float* __restrict__ v,
                                                    float* __restrict__ out) {
    __shared__ __align__(16) u16 y_lds[64 * 136];
    int t = threadIdx.x, b = blockIdx.y, n0 = blockIdx.x * 64;
    int z = blockIdx.z;
    int w = t >> 6, lane = t & 63, l15 = lane & 15, quad = lane >> 4;

#pragma unroll
    for (int i = 0; i < 4; i++) {
        int u = t + 256 * i;
        int row = u >> 4, blk = u & 15;
        *(uint4*)&y_lds[row * 136 + blk * 8] =
            *(const uint4*)&y[(size_t)(b * kN + n0 + row) * kCI + blk * 8];
    }
    __syncthreads();

    bf16x8 af[4];
#pragma unroll
    for (int ks = 0; ks < 4; ks++)
        af[ks] = *(const bf16x8*)&y_lds[(w * 16 + l15) * 136 + ks * 32 + quad * 8];

#pragma unroll
    for (int ct = 0; ct < 8; ct++) {
        int co = z * 128 + ct * 16 + l15;
        f32x4 a = (f32x4){0.f, 0.f, 0.f, 0.f};
#pragma unroll
        for (int ks = 0; ks < 4; ks++) {
            bf16x8 bf = *(const bf16x8*)&Wws[(size_t)co * kCI + ks * 32 + quad * 8];
            a = __builtin_amdgcn_mfma_f32_16x16x32_bf16(af[ks], bf, a, 0, 0, 0);
        }
        float bbv = bb[co];
        size_t base = (size_t)(b * kC + co) * kN + n0 + w * 16 + quad * 4;
        float4 vv = *(const float4*)&v[base];
        float4 ov;
        ov.x = a[0] + bbv + vv.x;
        ov.y = a[1] + bbv + vv.y;
        ov.z = a[2] + bbv + vv.z;
        ov.w = a[3] + bbv + vv.w;
        *(float4*)&out[base] = ov;
    }
}

// ---------------------------------------------------------------------------
extern "C" void kernel_launch(void* const* d_in, const int* in_sizes, int n_in,
                              void* d_out, int out_size, void* d_ws, size_t ws_size,
                              hipStream_t stream) {
    (void)in_sizes; (void)n_in; (void)out_size; (void)ws_size;
    const float* q     = (const float*)d_in[0];
    const float* k     = (const float*)d_in[1];
    const float* v     = (const float*)d_in[2];
    const float* Wg    = (const float*)d_in[3];
    const float* bg    = (const float*)d_in[4];
    const float* Wth   = (const float*)d_in[5];
    const float* bth   = (const float*)d_in[6];
    const float* Wph   = (const float*)d_in[7];
    const float* bph   = (const float*)d_in[8];
    const float* Ww    = (const float*)d_in[9];
    const float* bw    = (const float*)d_in[10];
    const float* gamma = (const float*)d_in[11];
    const float* beta  = (const float*)d_in[12];
    const float* mean  = (const float*)d_in[13];
    const float* var   = (const float*)d_in[14];
    float* out = (float*)d_out;

    u16* wsu = (u16*)d_ws;
    u16*   theta = wsu;                       // 4M u16 (8MB)
    u16*   phi   = theta + 4194304;           // 1M u16 (2MB)
    u16*   gbuf  = phi + 1048576;             // 1M u16 (2MB)
    u16*   ybuf  = gbuf + 1048576;            // 4M u16 (8MB)
    u16*   Wthb  = ybuf + 4194304;
    u16*   Wphb  = Wthb + 32768;
    u16*   Wgb   = Wphb + 32768;
    u16*   Wwsb  = Wgb + 32768;
    float* bbuf  = (float*)(Wwsb + 32768);    // 256 f32
    float* bthl  = bbuf + 256;                // 128 f32

    prep_kernel<<<dim3(512), 256, 0, stream>>>(Wth, bth, Wph, Wg, Ww, bw, gamma, beta,
                                               mean, var, Wthb, Wphb, Wgb, Wwsb,
                                               bbuf, bthl);
    convs_kernel<<<dim3(96, 8), 256, 0, stream>>>(q, k, v, Wthb, Wphb, Wgb,
                                                  bthl, bph, bg, theta, phi, gbuf);
    attn_kernel<<<dim3(64, 8), 256, 0, stream>>>(theta, phi, gbuf, ybuf);
    final_kernel<<<dim3(64, 8, 2), 256, 0, stream>>>(ybuf, Wwsb, bbuf, v, out);
}

// Round 7
// 225.187 us; speedup vs baseline: 1.2210x; 1.1319x over previous
//
#include <hip/hip_runtime.h>
#include <cstddef>

typedef unsigned short u16;
typedef unsigned int u32;
typedef __attribute__((ext_vector_type(8))) __bf16 bf16x8;
typedef __attribute__((ext_vector_type(4))) float f32x4;

constexpr int kB = 8, kC = 256, kCI = 128, kN = 4096, kM = 1024;
constexpr int kCH = 64, kNCH = kM / kCH;
constexpr float kEPS = 1e-5f;
constexpr float kLOG2E = 1.44269504088896f;

__device__ __forceinline__ u16 f2bf(float f) {
    u32 u = __float_as_uint(f);
    u32 r = (u + 0x7fffu + ((u >> 16) & 1u)) >> 16;
    return (u16)r;
}

__device__ __forceinline__ void gload_lds16(const u16* g, u16* l) {
    __builtin_amdgcn_global_load_lds(
        (const __attribute__((address_space(1))) void*)g,
        (__attribute__((address_space(3))) void*)l, 16, 0, 0);
}

// ---------------------------------------------------------------------------
// prep: weights -> bf16; fold BN scale into Ww; bb = (bw-mean)*sc+beta
// Wth/bth scaled by log2(e) so softmax runs in exp2 domain.
// ---------------------------------------------------------------------------
__global__ __launch_bounds__(256) void prep_kernel(const float* __restrict__ Wth,
                                                   const float* __restrict__ bth,
                                                   const float* __restrict__ Wph,
                                                   const float* __restrict__ Wg,
                                                   const float* __restrict__ Ww,
                                                   const float* __restrict__ bw,
                                                   const float* __restrict__ gamma,
                                                   const float* __restrict__ beta,
                                                   const float* __restrict__ mean,
                                                   const float* __restrict__ var,
                                                   u16* __restrict__ Wthb,
                                                   u16* __restrict__ Wphb,
                                                   u16* __restrict__ Wgb,
                                                   u16* __restrict__ Wwsb,
                                                   float* __restrict__ bb,
                                                   float* __restrict__ bthl) {
    int idx = blockIdx.x * 256 + threadIdx.x;
    if (idx < 32768) {
        Wthb[idx] = f2bf(Wth[idx] * kLOG2E);
        if (idx < kCI) bthl[idx] = bth[idx] * kLOG2E;
    } else if (idx < 65536) {
        int j = idx - 32768; Wphb[j] = f2bf(Wph[j]);
    } else if (idx < 98304) {
        int j = idx - 65536; Wgb[j] = f2bf(Wg[j]);
    } else {
        int j = idx - 98304;
        int co = j >> 7;
        float sc = gamma[co] * rsqrtf(var[co] + kEPS);
        Wwsb[j] = f2bf(Ww[j] * sc);
        if ((j & 127) == 0) bb[co] = (bw[co] - mean[co]) * sc + beta[co];
    }
}

// ---------------------------------------------------------------------------
// Whole-K conv1x1 body (r6 form, measured neutral-to-good): stage x tile
// (64 px x 256 c bf16 swizzled) once, one barrier, 8 K-steps with weight
// frags direct from global (L2-resident).
// ---------------------------------------------------------------------------
template <int POOL>
__device__ __forceinline__ void conv_body(const float* __restrict__ x,
                                          const u16* __restrict__ Wb,
                                          const float* __restrict__ bias,
                                          u16* __restrict__ out, int Mn,
                                          int cmajor, int b, int n0,
                                          u16* x_lds) {
    int t = threadIdx.x;
    int w = t >> 6, lane = t & 63, l15 = lane & 15, quad = lane >> 4;
    int px = t & 63, cb8 = t >> 6;

    for (int cc8 = 0; cc8 < 8; cc8++) {
        int cb = cb8 * 8 + cc8;
        int c0 = cb * 8;
        float f[8];
        if (POOL) {
            int p = n0 + px, ph_ = p >> 5, pw_ = p & 31;
#pragma unroll
            for (int j = 0; j < 8; j++) {
                const float* src = x + ((size_t)(b * kC + c0 + j) * 64
                                        + 2 * ph_) * 64 + 2 * pw_;
                float2 a = *(const float2*)src;
                float2 b2 = *(const float2*)(src + 64);
                f[j] = 0.25f * (a.x + a.y + b2.x + b2.y);
            }
        } else {
#pragma unroll
            for (int j = 0; j < 8; j++)
                f[j] = x[(size_t)(b * kC + c0 + j) * Mn + n0 + px];
        }
        uint4 pk;
        pk.x = (u32)f2bf(f[0]) | ((u32)f2bf(f[1]) << 16);
        pk.y = (u32)f2bf(f[2]) | ((u32)f2bf(f[3]) << 16);
        pk.z = (u32)f2bf(f[4]) | ((u32)f2bf(f[5]) << 16);
        pk.w = (u32)f2bf(f[6]) | ((u32)f2bf(f[7]) << 16);
        *(uint4*)&x_lds[px * 256 + ((cb ^ (px & 7)) * 8)] = pk;
    }
    __syncthreads();

    f32x4 acc[8];
#pragma unroll
    for (int i = 0; i < 8; i++) acc[i] = (f32x4){0.f, 0.f, 0.f, 0.f};

    int rpx = w * 16 + l15;
#pragma unroll
    for (int ks = 0; ks < 8; ks++) {
        bf16x8 xf = *(const bf16x8*)&x_lds[rpx * 256 +
                                           (((ks * 4 + quad) ^ (rpx & 7)) * 8)];
#pragma unroll
        for (int ct = 0; ct < 8; ct++) {
            bf16x8 wf = *(const bf16x8*)&Wb[(ct * 16 + l15) * kC + ks * 32 + quad * 8];
            if (cmajor)
                acc[ct] = __builtin_amdgcn_mfma_f32_16x16x32_bf16(xf, wf, acc[ct], 0, 0, 0);
            else
                acc[ct] = __builtin_amdgcn_mfma_f32_16x16x32_bf16(wf, xf, acc[ct], 0, 0, 0);
        }
    }

    if (cmajor == 0) {
        int opx = n0 + w * 16 + l15;
#pragma unroll
        for (int ct = 0; ct < 8; ct++) {
            int ci0 = ct * 16 + quad * 4;
            uint2 pk;
            pk.x = (u32)f2bf(acc[ct][0] + bias[ci0 + 0]) |
                   ((u32)f2bf(acc[ct][1] + bias[ci0 + 1]) << 16);
            pk.y = (u32)f2bf(acc[ct][2] + bias[ci0 + 2]) |
                   ((u32)f2bf(acc[ct][3] + bias[ci0 + 3]) << 16);
            *(uint2*)&out[(size_t)(b * Mn + opx) * kCI + ci0] = pk;
        }
    } else {
        int opx = n0 + w * 16 + quad * 4;
#pragma unroll
        for (int ct = 0; ct < 8; ct++) {
            int ci = ct * 16 + l15;
            float bs = bias[ci];
            uint2 pk;
            pk.x = (u32)f2bf(acc[ct][0] + bs) | ((u32)f2bf(acc[ct][1] + bs) << 16);
            pk.y = (u32)f2bf(acc[ct][2] + bs) | ((u32)f2bf(acc[ct][3] + bs) << 16);
            *(uint2*)&out[(size_t)(b * kCI + ci) * Mn + opx] = pk;
        }
    }
}

__global__ __launch_bounds__(256, 4) void convs_kernel(const float* __restrict__ q,
                                                       const float* __restrict__ k,
                                                       const float* __restrict__ v,
                                                       const u16* __restrict__ Wthb,
                                                       const u16* __restrict__ Wphb,
                                                       const u16* __restrict__ Wgb,
                                                       const float* __restrict__ bthl,
                                                       const float* __restrict__ bph,
                                                       const float* __restrict__ bg,
                                                       u16* __restrict__ theta,
                                                       u16* __restrict__ phi,
                                                       u16* __restrict__ g) {
    __shared__ __align__(16) u16 x_lds[64 * 256];
    int bx = blockIdx.x, b = blockIdx.y;
    if (bx < 64) {
        conv_body<0>(k, Wthb, bthl, theta, kN, 0, b, bx * 64, x_lds);
    } else {
        int z = (bx >= 80);
        int n0 = (z ? (bx - 80) : (bx - 64)) * 64;
        conv_body<1>(z ? v : q, z ? Wgb : Wphb, z ? bg : bph, z ? g : phi,
                     kM, z, b, n0, x_lds);
    }
}

// ---------------------------------------------------------------------------
// FUSED attention + final conv.
// Loop (r0/r6 proven compute structure) with ASYNC double-buffered staging:
// both phi and g chunks DMA'd via global_load_lds (linear LDS dest,
// inverse-swizzled per-lane global source), issued for chunk c+1 right
// after the single per-chunk barrier -> HBM/L2 latency hides under
// compute(c). exp2 domain + defer-max(8) + deferred l-reduce.
// Epilogue: y = O/l staged to an LDS tile (reusing phi buffers), then the
// final 1x1 conv (256 co, BN-folded Wws from L2) + bb + v -> out, in-block.
// LDS: phi 2x16KB + g 2x16KB + P 8KB = 72KB -> 2 blocks/CU (grid 2/CU).
// ---------------------------------------------------------------------------
__global__ __launch_bounds__(256) void attn_kernel(const u16* __restrict__ theta,
                                                   const u16* __restrict__ phi,
                                                   const u16* __restrict__ g,
                                                   const u16* __restrict__ Wws,
                                                   const float* __restrict__ bb,
                                                   const float* __restrict__ v,
                                                   float* __restrict__ out) {
    __shared__ __align__(16) u16 ph_lds[2][8192];  // [buf][ks:4][m:64][slot:4][8]
    __shared__ __align__(16) u16 g_lds[2][8192];   // [buf][ks2:2][ci:128][slot:4][8]
    __shared__ __align__(16) u16 p_lds[4096];      // [wave:4][frag:2][col:16][k:32]

    int t = threadIdx.x, b = blockIdx.y, n0 = blockIdx.x * 64;
    int w = t >> 6, lane = t & 63, l15 = lane & 15, quad = lane >> 4;
    int sw = (l15 >> 1) & 3;

    // theta B-frags in registers for the whole kernel (16 n per wave)
    bf16x8 thf[4];
    const u16* thB = theta + ((size_t)(b * kN) + n0 + w * 16 + l15) * kCI;
#pragma unroll
    for (int ks = 0; ks < 4; ks++)
        thf[ks] = *(const bf16x8*)&thB[ks * 32 + quad * 8];

    f32x4 oacc[8];
#pragma unroll
    for (int ct = 0; ct < 8; ct++) oacc[ct] = (f32x4){0.f, 0.f, 0.f, 0.f};
    float m_ = -1e30f, l_ = 0.f;

    const u16* phB = phi + (size_t)b * kM * kCI;
    const u16* gB  = g   + (size_t)b * kCI * kM;
    u16* pw = p_lds + w * 1024;

    // async stage chunk ch into buf: dst slot W = i*256 + w*64 + lane
    // (wave-uniform base + lane*16B); source decoded from W (inverse swz).
    auto STAGE = [&](int buf, int ch) {
        int c0 = ch * kCH;
#pragma unroll
        for (int i = 0; i < 4; i++) {
            int W = t + 256 * i;
            int ks = W >> 8, m = (W >> 2) & 63, sl = W & 3;
            int cb = (ks << 2) | (sl ^ ((m >> 1) & 3));
            gload_lds16(phB + (size_t)(c0 + m) * kCI + cb * 8,
                        &ph_lds[buf][(w * 64 + i * 256) * 8]);
        }
#pragma unroll
        for (int i = 0; i < 4; i++) {
            int W = t + 256 * i;
            int ks2 = W >> 9, ci = (W >> 2) & 127, sl = W & 3;
            int mb = (ks2 << 2) | (sl ^ ((ci >> 1) & 3));
            gload_lds16(gB + (size_t)ci * kM + c0 + mb * 8,
                        &g_lds[buf][(w * 64 + i * 256) * 8]);
        }
    };

    STAGE(0, 0);

    for (int ch = 0; ch < kNCH; ++ch) {
        asm volatile("s_waitcnt vmcnt(0)" ::: "memory");
        __syncthreads();   // chunk ch landed; all reads of target buf done
        if (ch + 1 < kNCH) STAGE((ch + 1) & 1, ch + 1);
        const u16* phb = ph_lds[ch & 1];
        const u16* glb = g_lds[ch & 1];

        // S' = phi(64m x 128k) . theta^T : 4 mt-tiles, C-col = n (exp2 dom)
        f32x4 sacc[4];
#pragma unroll
        for (int mt = 0; mt < 4; mt++) sacc[mt] = (f32x4){0.f, 0.f, 0.f, 0.f};
#pragma unroll
        for (int ks = 0; ks < 4; ks++)
#pragma unroll
            for (int mt = 0; mt < 4; mt++) {
                bf16x8 a = *(const bf16x8*)&phb[ks * 2048 + (mt * 16 + l15) * 32 +
                                                ((quad ^ sw) * 8)];
                sacc[mt] = __builtin_amdgcn_mfma_f32_16x16x32_bf16(a, thf[ks], sacc[mt], 0, 0, 0);
            }

        // online softmax (exp2 domain, defer-max(8), per-lane partial l)
        float mc = -1e30f;
#pragma unroll
        for (int mt = 0; mt < 4; mt++)
#pragma unroll
            for (int r = 0; r < 4; r++) mc = fmaxf(mc, sacc[mt][r]);
        mc = fmaxf(mc, __shfl_xor(mc, 16, 64));
        mc = fmaxf(mc, __shfl_xor(mc, 32, 64));
        if (__any(mc > m_ + 8.0f)) {
            float mn = fmaxf(m_, mc);
            float al = exp2f(m_ - mn);
            m_ = mn;
            l_ *= al;
#pragma unroll
            for (int ct = 0; ct < 8; ct++)
#pragma unroll
                for (int r = 0; r < 4; r++) oacc[ct][r] *= al;
        }
        float rs = 0.f;
#pragma unroll
        for (int mt = 0; mt < 4; mt++)
#pragma unroll
            for (int r = 0; r < 4; r++) {
                float p = exp2f(sacc[mt][r] - m_);
                sacc[mt][r] = p;
                rs += p;
            }
        l_ += rs;

        // scatter P' -> per-wave frag LDS
#pragma unroll
        for (int mt = 0; mt < 4; mt++)
#pragma unroll
            for (int h = 0; h < 2; h++) {
                u32 d = (u32)f2bf(sacc[mt][2 * h]) | ((u32)f2bf(sacc[mt][2 * h + 1]) << 16);
                int m = mt * 16 + quad * 4 + 2 * h;
                int frag = m >> 5;
                int kblk = ((m >> 3) & 3);
                int j = (quad & 1) * 4 + 2 * h;
                *(u32*)&pw[frag * 512 + l15 * 32 + ((kblk ^ sw) * 8) + j] = d;
            }

        // O' += G^T(128ci x 64m) . P'
#pragma unroll
        for (int ks2 = 0; ks2 < 2; ks2++) {
            bf16x8 bfrag = *(const bf16x8*)&pw[ks2 * 512 + l15 * 32 + ((quad ^ sw) * 8)];
#pragma unroll
            for (int ct = 0; ct < 8; ct++) {
                bf16x8 a = *(const bf16x8*)&glb[ks2 * 4096 + (ct * 16 + l15) * 32 +
                                                ((quad ^ sw) * 8)];
                oacc[ct] = __builtin_amdgcn_mfma_f32_16x16x32_bf16(a, bfrag, oacc[ct], 0, 0, 0);
            }
        }
    }

    // ---- fused final conv epilogue ----
    l_ += __shfl_xor(l_, 16, 64);
    l_ += __shfl_xor(l_, 32, 64);
    float inv = 1.0f / l_;

    __syncthreads();                      // all chunk compute done; LDS free
    u16* y_lds = &ph_lds[0][0];           // [64 n][136 ci-padded] (17KB)
    int nrow = w * 16 + l15;              // C-col = n within tile
#pragma unroll
    for (int ct = 0; ct < 8; ct++) {
        uint2 pk;
        pk.x = (u32)f2bf(oacc[ct][0] * inv) | ((u32)f2bf(oacc[ct][1] * inv) << 16);
        pk.y = (u32)f2bf(oacc[ct][2] * inv) | ((u32)f2bf(oacc[ct][3] * inv) << 16);
        *(uint2*)&y_lds[nrow * 136 + ct * 16 + quad * 4] = pk;
    }
    __syncthreads();

    bf16x8 af[4];
#pragma unroll
    for (int ks = 0; ks < 4; ks++)
        af[ks] = *(const bf16x8*)&y_lds[nrow * 136 + ks * 32 + quad * 8];

#pragma unroll
    for (int ct = 0; ct < 16; ct++) {
        int co = ct * 16 + l15;
        f32x4 a = (f32x4){0.f, 0.f, 0.f, 0.f};
#pragma unroll
        for (int ks = 0; ks < 4; ks++) {
            bf16x8 bf = *(const bf16x8*)&Wws[(size_t)co * kCI + ks * 32 + quad * 8];
            a = __builtin_amdgcn_mfma_f32_16x16x32_bf16(af[ks], bf, a, 0, 0, 0);
        }
        float bbv = bb[co];
        size_t base = (size_t)(b * kC + co) * kN + n0 + w * 16 + quad * 4;
        float4 vv = *(const float4*)&v[base];
        float4 ov;
        ov.x = a[0] + bbv + vv.x;
        ov.y = a[1] + bbv + vv.y;
        ov.z = a[2] + bbv + vv.z;
        ov.w = a[3] + bbv + vv.w;
        *(float4*)&out[base] = ov;
    }
}

// ---------------------------------------------------------------------------
extern "C" void kernel_launch(void* const* d_in, const int* in_sizes, int n_in,
                              void* d_out, int out_size, void* d_ws, size_t ws_size,
                              hipStream_t stream) {
    (void)in_sizes; (void)n_in; (void)out_size; (void)ws_size;
    const float* q     = (const float*)d_in[0];
    const float* k     = (const float*)d_in[1];
    const float* v     = (const float*)d_in[2];
    const float* Wg    = (const float*)d_in[3];
    const float* bg    = (const float*)d_in[4];
    const float* Wth   = (const float*)d_in[5];
    const float* bth   = (const float*)d_in[6];
    const float* Wph   = (const float*)d_in[7];
    const float* bph   = (const float*)d_in[8];
    const float* Ww    = (const float*)d_in[9];
    const float* bw    = (const float*)d_in[10];
    const float* gamma = (const float*)d_in[11];
    const float* beta  = (const float*)d_in[12];
    const float* mean  = (const float*)d_in[13];
    const float* var   = (const float*)d_in[14];
    float* out = (float*)d_out;

    u16* wsu = (u16*)d_ws;
    u16*   theta = wsu;                       // 4M u16 (8MB)
    u16*   phi   = theta + 4194304;           // 1M u16 (2MB)
    u16*   gbuf  = phi + 1048576;             // 1M u16 (2MB)
    u16*   Wthb  = gbuf + 1048576;
    u16*   Wphb  = Wthb + 32768;
    u16*   Wgb   = Wphb + 32768;
    u16*   Wwsb  = Wgb + 32768;
    float* bbuf  = (float*)(Wwsb + 32768);    // 256 f32
    float* bthl  = bbuf + 256;                // 128 f32

    prep_kernel<<<dim3(512), 256, 0, stream>>>(Wth, bth, Wph, Wg, Ww, bw, gamma, beta,
                                               mean, var, Wthb, Wphb, Wgb, Wwsb,
                                               bbuf, bthl);
    convs_kernel<<<dim3(96, 8), 256, 0, stream>>>(q, k, v, Wthb, Wphb, Wgb,
                                                  bthl, bph, bg, theta, phi, gbuf);
    attn_kernel<<<dim3(64, 8), 256, 0, stream>>>(theta, phi, gbuf, Wwsb, bbuf, v, out);
}